// Round 4
// baseline (554.966 us; speedup 1.0000x reference)
//
#include <hip/hip_runtime.h>
#include <hip/hip_bf16.h>
#include <stdint.h>

// ---------------------------------------------------------------------------
// QuantGRU: T=512, B=64, I=256, H=256. ACT scale 2^-7, W scale 2^-8.
// Exact integer arithmetic; sigmoid/tanh via 256-entry f64-built LUTs.
// Recurrence: 8 waves/block, K-split 2-way; h broadcast via readlane->SGPR;
// integer partial sums combined through LDS (exactness preserved).
// ---------------------------------------------------------------------------

#define T_STEPS 512
#define BATCH   64
#define IDIM    256
#define HDIM    256
#define N3H     768   // 3*H

#if defined(__has_builtin)
#if __has_builtin(__builtin_amdgcn_sdot4)
#define DOT4(a,b,c) __builtin_amdgcn_sdot4((int)(a),(int)(b),(int)(c),false)
#endif
#endif
#ifndef DOT4
__device__ __forceinline__ int dot4_sw(uint32_t a, uint32_t b, int c){
  c += (int)(int8_t)(a)      * (int)(int8_t)(b);
  c += (int)(int8_t)(a>>8)   * (int)(int8_t)(b>>8);
  c += (int)(int8_t)(a>>16)  * (int)(int8_t)(b>>16);
  c += (int)(int8_t)(a>>24)  * (int)(int8_t)(b>>24);
  return c;
}
#define DOT4(a,b,c) dot4_sw((uint32_t)(a),(uint32_t)(b),(int)(c))
#endif

// select dword component of a uint4 by compile-time constant (stays in VGPRs)
#define CHUNK(W,c) (((c)&3)==0 ? W[(c)>>2].x : ((c)&3)==1 ? W[(c)>>2].y : \
                    ((c)&3)==2 ? W[(c)>>2].z : W[(c)>>2].w)

// round-to-nearest-even + clamp to int8 range (matches jnp.round + clip)
__device__ __forceinline__ int rneclamp(float v) {
  int q = (int)rintf(v);
  return min(127, max(-128, q));
}

__device__ __forceinline__ uint32_t packq4(float4 f, float sc) {
  uint32_t b0 = (uint32_t)(uint8_t)(int8_t)rneclamp(f.x * sc);
  uint32_t b1 = (uint32_t)(uint8_t)(int8_t)rneclamp(f.y * sc);
  uint32_t b2 = (uint32_t)(uint8_t)(int8_t)rneclamp(f.z * sc);
  uint32_t b3 = (uint32_t)(uint8_t)(int8_t)rneclamp(f.w * sc);
  return b0 | (b1 << 8) | (b2 << 16) | (b3 << 24);
}

// ---------------------------------------------------------------------------
// prep: quantize W to k-chunk-transposed layout (for gemm_wx coalesced loads),
// R to plain COLUMN-MAJOR (Rq[col*256 + k]), biases to int8.
// ---------------------------------------------------------------------------
__global__ void prep_kernel(const float* __restrict__ W, const float* __restrict__ R,
                            const float* __restrict__ bx, const float* __restrict__ br,
                            int8_t* __restrict__ Wq, int8_t* __restrict__ Rq,
                            int8_t* __restrict__ bx8, int8_t* __restrict__ br8) {
  const int NW = IDIM * N3H; // 196608
  int idx = blockIdx.x * 256 + threadIdx.x;
  if (idx < NW) {
    int k = idx / N3H, j = idx % N3H;
    Wq[((size_t)(k >> 4) * N3H + j) * 16 + (k & 15)] = (int8_t)rneclamp(W[idx] * 256.0f);
  } else if (idx < 2 * NW) {
    int i2 = idx - NW;
    int k = i2 / N3H, j = i2 % N3H;
    Rq[(size_t)j * HDIM + k] = (int8_t)rneclamp(R[i2] * 256.0f);   // col-major
  } else if (idx < 2 * NW + N3H) {
    int i2 = idx - 2 * NW;
    bx8[i2] = (int8_t)rneclamp(bx[i2] * 256.0f);
  } else if (idx < 2 * NW + 2 * N3H) {
    int i2 = idx - 2 * NW - N3H;
    br8[i2] = (int8_t)rneclamp(br[i2] * 256.0f);
  }
}

// ---------------------------------------------------------------------------
// gemm_wx: Wx_q[b][t][j] = clamp(rne( (fq(x) . Wq col j) / 256 ))  (int8)
// one block per t (64 rows), 768 threads = one per output column.
// ---------------------------------------------------------------------------
__global__ __launch_bounds__(768, 1) void gemm_wx_kernel(
    const float* __restrict__ x, const int8_t* __restrict__ Wq,
    int8_t* __restrict__ WxQ8) {
  const int t = blockIdx.x;   // 0..511
  const int j = threadIdx.x;  // 0..767

  __shared__ uint4 xq4[64 * 16];   // 64 rows x 256 int8 = 16KB
  uint32_t* xq = (uint32_t*)xq4;

  // weights for column j: 16 uint4, coalesced from transposed layout
  uint4 w[16];
  const uint4* wp = (const uint4*)Wq;
  #pragma unroll
  for (int kk = 0; kk < 16; ++kk) w[kk] = wp[kk * N3H + j];

  // stage + quantize x tile: rows = x[t][b][:], b=0..63
  const float4* xg = (const float4*)(x) + (size_t)t * 4096;
  for (int i = j; i < 4096; i += 768) {
    float4 f = xg[i];
    xq[i] = packq4(f, 128.0f);
  }
  __syncthreads();

  for (int r = 0; r < 64; ++r) {
    int s = 0;
    #pragma unroll
    for (int kk = 0; kk < 16; ++kk) {
      uint4 hv = xq4[r * 16 + kk];
      s = DOT4(hv.x, w[kk].x, s);
      s = DOT4(hv.y, w[kk].y, s);
      s = DOT4(hv.z, w[kk].z, s);
      s = DOT4(hv.w, w[kk].w, s);
    }
    int q = rneclamp((float)s * (1.0f / 256.0f));
    WxQ8[((size_t)r * T_STEPS + t) * N3H + j] = (int8_t)q;
  }
}

// ---------------------------------------------------------------------------
// gru_rec3: one block per batch element; 512 threads = 8 waves.
// Thread (half, j): partial GEMV of cols {j, j+256, j+512} over K-half.
// half-1 writes raw int partials to LDS; half-0 sums + gates + h update.
// ---------------------------------------------------------------------------
__global__ __launch_bounds__(512, 2) void gru_rec3_kernel(
    const float* __restrict__ h0, const int8_t* __restrict__ Rq,
    const int8_t* __restrict__ bx8, const int8_t* __restrict__ br8,
    const int8_t* __restrict__ WxQ8, float* __restrict__ out) {
  const int b    = blockIdx.x;      // batch element
  const int tid  = threadIdx.x;     // 0..511
  const int lane = tid & 63;
  const int half = tid >> 8;        // 0 or 1 (K-half)
  const int j    = tid & 255;       // h index / col base

  __shared__ uint32_t hq[2][64];    // double-buffered int8 h (256 B each)
  __shared__ int part[N3H];         // half-1 raw partial sums
  __shared__ int8_t lutS[256];
  __shared__ int8_t lutT[256];

  // weights: cols j, j+256, j+512; this thread's K-half = 8 uint4 per col
  uint4 wz[8], wr[8], wg[8];
  {
    const uint4* pz = (const uint4*)(Rq + (size_t)j * HDIM)         + half * 8;
    const uint4* pr = (const uint4*)(Rq + (size_t)(j + 256) * HDIM) + half * 8;
    const uint4* pg = (const uint4*)(Rq + (size_t)(j + 512) * HDIM) + half * 8;
    #pragma unroll
    for (int kk = 0; kk < 8; ++kk) { wz[kk] = pz[kk]; wr[kk] = pr[kk]; wg[kk] = pg[kk]; }
  }

  // gate-thread (half-0) persistent state
  float hf = 0.0f;
  int bz = 0, brg = 0, bg = 0, vbz = 0, vbr = 0, vbg = 0;
  const int8_t* wxp = WxQ8 + (size_t)b * T_STEPS * N3H + j;
  int wxA0 = 0, wxA1 = 0, wxA2 = 0;   // step t
  int wxB0 = 0, wxB1 = 0, wxB2 = 0;   // step t+1
  if (!half) {
    bz  = (int)bx8[j];
    brg = (int)bx8[j + 256];
    bg  = (int)bx8[j + 512];
    vbz = (int)br8[j];
    vbr = (int)br8[j + 256];
    vbg = (int)br8[j + 512];
    // LUTs in f64 (inputs are fq-clamped to k/128, k in [-128,127])
    double a = ((double)j - 128.0) / 128.0;
    lutS[j] = (int8_t)min(127, max(-128, (int)rint(128.0 / (1.0 + exp(-a)))));
    lutT[j] = (int8_t)min(127, max(-128, (int)rint(128.0 * tanh(a))));
    hf = h0[b * HDIM + j];
    ((int8_t*)&hq[0][0])[j] = (int8_t)rneclamp(hf * 128.0f);
    // prefetch Wx for t=0 and t=1
    wxA0 = (int)wxp[0];   wxA1 = (int)wxp[256];        wxA2 = (int)wxp[512];
    wxB0 = (int)wxp[N3H]; wxB1 = (int)wxp[N3H + 256];  wxB2 = (int)wxp[N3H + 512];
  }
  __syncthreads();

  float* outp = out + (size_t)b * HDIM + j;

  for (int t = 0; t < T_STEPS; ++t) {
    const int cur = t & 1, nxt = cur ^ 1;

    // issue Wx loads for t+2 immediately (2 steps in flight hides HBM miss)
    int nz = 0, nr = 0, ng = 0;
    if (!half) {
      const int8_t* p = wxp + (size_t)min(t + 2, T_STEPS - 1) * N3H;
      nz = (int)p[0]; nr = (int)p[256]; ng = (int)p[512];
    }

    // ---- GEMV partial: h chunks via readlane -> SGPR, dot4 vs reg weights
    uint32_t hw = hq[cur][half * 32 + (lane & 31)];
    int sz = 0, sr = 0, sg = 0;
    #pragma unroll
    for (int c = 0; c < 32; ++c) {
      int hc = __builtin_amdgcn_readlane((int)hw, c);
      sz = DOT4(hc, CHUNK(wz, c), sz);
      sr = DOT4(hc, CHUNK(wr, c), sr);
      sg = DOT4(hc, CHUNK(wg, c), sg);
    }
    if (half) { part[j] = sz; part[j + 256] = sr; part[j + 512] = sg; }
    __syncthreads();

    if (!half) {
      sz += part[j]; sr += part[j + 256]; sg += part[j + 512];
      // Rh = fq(hq@Rq,7): rne(s/256); v = fq(Rh+brq,7): rne((2Rh+br)/2)
      int Rz = rneclamp((float)sz * (1.0f / 256.0f));
      int Rr = rneclamp((float)sr * (1.0f / 256.0f));
      int Rg = rneclamp((float)sg * (1.0f / 256.0f));
      int vz = rneclamp((float)(2 * Rz + vbz) * 0.5f);
      int vr = rneclamp((float)(2 * Rr + vbr) * 0.5f);
      int vg = rneclamp((float)(2 * Rg + vbg) * 0.5f);
      // gates (all local to this thread)
      int az = rneclamp((float)(2 * wxA0 + bz + 2 * vz) * 0.5f);
      int zi = (int)lutS[az + 128];
      int ar = rneclamp((float)(2 * wxA1 + brg + 2 * vr) * 0.5f);
      int ri = (int)lutS[ar + 128];
      int rrh = rneclamp((float)(ri * vg) * (1.0f / 128.0f));
      int ag = rneclamp((float)(2 * wxA2 + bg + 2 * rrh) * 0.5f);
      int gi = (int)lutT[ag + 128];
      int oldi = rneclamp((float)zi * hf);
      int newi = rneclamp((float)((128 - zi) * gi) * (1.0f / 128.0f));
      int hi = oldi + newi;              // integer, units 1/128
      hf = (float)hi * (1.0f / 128.0f);
      outp[(size_t)t * BATCH * HDIM] = hf;   // out[t][b][j]
      ((int8_t*)&hq[nxt][0])[j] = (int8_t)min(127, max(-128, hi));
      // advance Wx pipeline
      wxA0 = wxB0; wxA1 = wxB1; wxA2 = wxB2;
      wxB0 = nz;   wxB1 = nr;   wxB2 = ng;
    }
    __syncthreads();
  }
}

// ---------------------------------------------------------------------------
extern "C" void kernel_launch(void* const* d_in, const int* in_sizes, int n_in,
                              void* d_out, int out_size, void* d_ws, size_t ws_size,
                              hipStream_t stream) {
  const float* x  = (const float*)d_in[0];   // (T,B,I)
  const float* h0 = (const float*)d_in[1];   // (B,H)
  const float* W  = (const float*)d_in[2];   // (I,3H)
  const float* R  = (const float*)d_in[3];   // (H,3H)
  const float* bx = (const float*)d_in[4];   // (3H,)
  const float* br = (const float*)d_in[5];   // (3H,)
  float* out = (float*)d_out;                // (T,B,H)

  // workspace layout
  const size_t NW = (size_t)IDIM * N3H;          // 196608
  int8_t* Wq  = (int8_t*)d_ws;                   // 196608
  int8_t* Rq  = Wq + NW;                         // 196608
  int8_t* bx8 = Rq + NW;                         // 768
  int8_t* br8 = bx8 + N3H;                       // 768
  int8_t* WxQ8 = br8 + N3H;                      // 64*512*768 = 25165824

  {
    int total = (int)(2 * NW + 2 * N3H);
    int blocks = (total + 255) / 256;
    prep_kernel<<<blocks, 256, 0, stream>>>(W, R, bx, br, Wq, Rq, bx8, br8);
  }
  gemm_wx_kernel<<<T_STEPS, 768, 0, stream>>>(x, Wq, WxQ8);
  gru_rec3_kernel<<<BATCH, 512, 0, stream>>>(h0, Rq, bx8, br8, WxQ8, out);
}

// Round 5
// 507.412 us; speedup vs baseline: 1.0937x; 1.0937x over previous
//
#include <hip/hip_runtime.h>
#include <hip/hip_bf16.h>
#include <stdint.h>

// ---------------------------------------------------------------------------
// QuantGRU: T=512, B=64, I=256, H=256. ACT scale 2^-7, W scale 2^-8.
// Exact integer arithmetic; sigmoid/tanh via 256-entry f64-built LUTs.
// Recurrence: 256 thr/block (4 waves), h broadcast via readlane->SGPR->dot4.
// Per-step sync is an LDS-ONLY barrier (s_waitcnt lgkmcnt(0); s_barrier) so
// out-stores and Wx prefetch loads stay in flight across steps (no vmcnt(0)
// drain -- that drain was ~1000 cyc/step in the previous version).
// ---------------------------------------------------------------------------

#define T_STEPS 512
#define BATCH   64
#define IDIM    256
#define HDIM    256
#define N3H     768   // 3*H

#if defined(__has_builtin)
#if __has_builtin(__builtin_amdgcn_sdot4)
#define DOT4(a,b,c) __builtin_amdgcn_sdot4((int)(a),(int)(b),(int)(c),false)
#endif
#endif
#ifndef DOT4
__device__ __forceinline__ int dot4_sw(uint32_t a, uint32_t b, int c){
  c += (int)(int8_t)(a)      * (int)(int8_t)(b);
  c += (int)(int8_t)(a>>8)   * (int)(int8_t)(b>>8);
  c += (int)(int8_t)(a>>16)  * (int)(int8_t)(b>>16);
  c += (int)(int8_t)(a>>24)  * (int)(int8_t)(b>>24);
  return c;
}
#define DOT4(a,b,c) dot4_sw((uint32_t)(a),(uint32_t)(b),(int)(c))
#endif

// select dword component of a uint4 by compile-time constant (stays in VGPRs)
#define CHUNK(W,c) (((c)&3)==0 ? W[(c)>>2].x : ((c)&3)==1 ? W[(c)>>2].y : \
                    ((c)&3)==2 ? W[(c)>>2].z : W[(c)>>2].w)

// LDS-only workgroup barrier: does NOT drain vmcnt (global loads/stores
// stay in flight). All LDS writes are committed (lgkmcnt) then sync.
__device__ __forceinline__ void barrier_lds() {
  asm volatile("s_waitcnt lgkmcnt(0)\n\ts_barrier" ::: "memory");
}

// round-to-nearest-even + clamp to int8 range (matches jnp.round + clip)
__device__ __forceinline__ int rneclamp(float v) {
  int q = (int)rintf(v);
  return min(127, max(-128, q));
}

__device__ __forceinline__ uint32_t packq4(float4 f, float sc) {
  uint32_t b0 = (uint32_t)(uint8_t)(int8_t)rneclamp(f.x * sc);
  uint32_t b1 = (uint32_t)(uint8_t)(int8_t)rneclamp(f.y * sc);
  uint32_t b2 = (uint32_t)(uint8_t)(int8_t)rneclamp(f.z * sc);
  uint32_t b3 = (uint32_t)(uint8_t)(int8_t)rneclamp(f.w * sc);
  return b0 | (b1 << 8) | (b2 << 16) | (b3 << 24);
}

// ---------------------------------------------------------------------------
// prep: W -> k-chunk-transposed int8 (for gemm_wx coalesced column loads),
// R -> plain column-major int8, biases -> int8.
// ---------------------------------------------------------------------------
__global__ void prep_kernel(const float* __restrict__ W, const float* __restrict__ R,
                            const float* __restrict__ bx, const float* __restrict__ br,
                            int8_t* __restrict__ Wq, int8_t* __restrict__ Rq,
                            int8_t* __restrict__ bx8, int8_t* __restrict__ br8) {
  const int NW = IDIM * N3H; // 196608
  int idx = blockIdx.x * 256 + threadIdx.x;
  if (idx < NW) {
    int k = idx / N3H, j = idx % N3H;
    Wq[((size_t)(k >> 4) * N3H + j) * 16 + (k & 15)] = (int8_t)rneclamp(W[idx] * 256.0f);
  } else if (idx < 2 * NW) {
    int i2 = idx - NW;
    int k = i2 / N3H, j = i2 % N3H;
    Rq[(size_t)j * HDIM + k] = (int8_t)rneclamp(R[i2] * 256.0f);   // col-major
  } else if (idx < 2 * NW + N3H) {
    int i2 = idx - 2 * NW;
    bx8[i2] = (int8_t)rneclamp(bx[i2] * 256.0f);
  } else if (idx < 2 * NW + 2 * N3H) {
    int i2 = idx - 2 * NW - N3H;
    br8[i2] = (int8_t)rneclamp(br[i2] * 256.0f);
  }
}

// ---------------------------------------------------------------------------
// gemm_wx: Wx_q[b][t][j] = clamp(rne( (fq(x) . Wq col j) / 256 ))  (int8)
// one block per t (64 rows), 768 threads = one per output column.
// ---------------------------------------------------------------------------
__global__ __launch_bounds__(768, 1) void gemm_wx_kernel(
    const float* __restrict__ x, const int8_t* __restrict__ Wq,
    int8_t* __restrict__ WxQ8) {
  const int t = blockIdx.x;   // 0..511
  const int j = threadIdx.x;  // 0..767

  __shared__ uint4 xq4[64 * 16];   // 64 rows x 256 int8 = 16KB
  uint32_t* xq = (uint32_t*)xq4;

  // weights for column j: 16 uint4, coalesced from transposed layout
  uint4 w[16];
  const uint4* wp = (const uint4*)Wq;
  #pragma unroll
  for (int kk = 0; kk < 16; ++kk) w[kk] = wp[kk * N3H + j];

  // stage + quantize x tile: rows = x[t][b][:], b=0..63
  const float4* xg = (const float4*)(x) + (size_t)t * 4096;
  for (int i = j; i < 4096; i += 768) {
    float4 f = xg[i];
    xq[i] = packq4(f, 128.0f);
  }
  __syncthreads();

  for (int r = 0; r < 64; ++r) {
    int s = 0;
    #pragma unroll
    for (int kk = 0; kk < 16; ++kk) {
      uint4 hv = xq4[r * 16 + kk];
      s = DOT4(hv.x, w[kk].x, s);
      s = DOT4(hv.y, w[kk].y, s);
      s = DOT4(hv.z, w[kk].z, s);
      s = DOT4(hv.w, w[kk].w, s);
    }
    int q = rneclamp((float)s * (1.0f / 256.0f));
    WxQ8[((size_t)r * T_STEPS + t) * N3H + j] = (int8_t)q;
  }
}

// ---------------------------------------------------------------------------
// gru_rec4: one block per batch element; 256 threads (4 waves), thread j owns
// h[j] and its gate triple (columns j, j+256, j+512 of R).
// ---------------------------------------------------------------------------
__global__ __launch_bounds__(256, 1) void gru_rec4_kernel(
    const float* __restrict__ h0, const int8_t* __restrict__ Rq,
    const int8_t* __restrict__ bx8, const int8_t* __restrict__ br8,
    const int8_t* __restrict__ WxQ8, float* __restrict__ out) {
  const int b = blockIdx.x;     // batch element
  const int j = threadIdx.x;    // 0..255
  const int lane = j & 63;

  __shared__ uint32_t hq[2][64];    // double-buffered int8 h (256 B each)
  __shared__ int8_t lutS[256];
  __shared__ int8_t lutT[256];

  // R columns j, j+256, j+512 in registers: 3 x 16 uint4 = 192 VGPRs
  uint4 wz[16], wr[16], wg[16];
  {
    const uint4* pz = (const uint4*)(Rq + (size_t)j * HDIM);
    const uint4* pr = (const uint4*)(Rq + (size_t)(j + 256) * HDIM);
    const uint4* pg = (const uint4*)(Rq + (size_t)(j + 512) * HDIM);
    #pragma unroll
    for (int kk = 0; kk < 16; ++kk) { wz[kk] = pz[kk]; wr[kk] = pr[kk]; wg[kk] = pg[kk]; }
  }
  const int bz  = (int)bx8[j];
  const int brg = (int)bx8[j + 256];
  const int bg  = (int)bx8[j + 512];
  const int vbz = (int)br8[j];
  const int vbr = (int)br8[j + 256];
  const int vbg = (int)br8[j + 512];

  // LUTs in f64 (inputs are fq-clamped to k/128, k in [-128,127])
  {
    double a = ((double)j - 128.0) / 128.0;
    lutS[j] = (int8_t)min(127, max(-128, (int)rint(128.0 / (1.0 + exp(-a)))));
    lutT[j] = (int8_t)min(127, max(-128, (int)rint(128.0 * tanh(a))));
  }
  float hf = h0[b * HDIM + j];
  ((int8_t*)&hq[0][0])[j] = (int8_t)rneclamp(hf * 128.0f);
  __syncthreads();

  const int8_t* wxp = WxQ8 + (size_t)b * T_STEPS * N3H + j;
  float* outp = out + (size_t)b * HDIM + j;

  // Wx 2-deep prefetch pipeline: A = step t, B = step t+1
  int wxA0 = (int)wxp[0],   wxA1 = (int)wxp[256],       wxA2 = (int)wxp[512];
  int wxB0 = (int)wxp[N3H], wxB1 = (int)wxp[N3H + 256], wxB2 = (int)wxp[N3H + 512];

  for (int t = 0; t < T_STEPS; ++t) {
    const int cur = t & 1, nxt = cur ^ 1;

    // issue Wx loads for t+2 FIRST (oldest in vmcnt queue; ~2 steps in flight)
    int nz, nr, ng;
    {
      const int8_t* p = wxp + (size_t)min(t + 2, T_STEPS - 1) * N3H;
      nz = (int)p[0]; nr = (int)p[256]; ng = (int)p[512];
    }

    // ---- GEMV: h broadcast via readlane -> SGPR, dot4 against reg weights
    uint32_t hw = hq[cur][lane];      // one ds_read_b32 per wave
    int sz = 0, sr = 0, sg = 0;
    #pragma unroll
    for (int c = 0; c < 64; ++c) {
      int hc = __builtin_amdgcn_readlane((int)hw, c);
      sz = DOT4(hc, CHUNK(wz, c), sz);
      sr = DOT4(hc, CHUNK(wr, c), sr);
      sg = DOT4(hc, CHUNK(wg, c), sg);
    }
    // Rh = fq(hq@Rq,7): rne(s/256); v = fq(Rh+brq,7): rne((2Rh+br)/2)
    int Rz = rneclamp((float)sz * (1.0f / 256.0f));
    int Rr = rneclamp((float)sr * (1.0f / 256.0f));
    int Rg = rneclamp((float)sg * (1.0f / 256.0f));
    int vz = rneclamp((float)(2 * Rz + vbz) * 0.5f);
    int vr = rneclamp((float)(2 * Rr + vbr) * 0.5f);
    int vg = rneclamp((float)(2 * Rg + vbg) * 0.5f);

    // ---- gates (all local to this thread)
    int az = rneclamp((float)(2 * wxA0 + bz + 2 * vz) * 0.5f);
    int zi = (int)lutS[az + 128];
    int ar = rneclamp((float)(2 * wxA1 + brg + 2 * vr) * 0.5f);
    int ri = (int)lutS[ar + 128];
    int rrh = rneclamp((float)(ri * vg) * (1.0f / 128.0f));
    int ag = rneclamp((float)(2 * wxA2 + bg + 2 * rrh) * 0.5f);
    int gi = (int)lutT[ag + 128];
    int oldi = rneclamp((float)zi * hf);
    int newi = rneclamp((float)((128 - zi) * gi) * (1.0f / 128.0f));
    int hi = oldi + newi;              // integer, units 1/128
    hf = (float)hi * (1.0f / 128.0f);
    outp[(size_t)t * BATCH * HDIM] = hf;   // out[t][b][j] (fire-and-forget)
    ((int8_t*)&hq[nxt][0])[j] = (int8_t)min(127, max(-128, hi));

    // advance Wx pipeline
    wxA0 = wxB0; wxA1 = wxB1; wxA2 = wxB2;
    wxB0 = nz;   wxB1 = nr;   wxB2 = ng;

    // LDS-only barrier: hq[nxt] visible to all waves; vmcnt NOT drained.
    barrier_lds();
  }
}

// ---------------------------------------------------------------------------
extern "C" void kernel_launch(void* const* d_in, const int* in_sizes, int n_in,
                              void* d_out, int out_size, void* d_ws, size_t ws_size,
                              hipStream_t stream) {
  const float* x  = (const float*)d_in[0];   // (T,B,I)
  const float* h0 = (const float*)d_in[1];   // (B,H)
  const float* W  = (const float*)d_in[2];   // (I,3H)
  const float* R  = (const float*)d_in[3];   // (H,3H)
  const float* bx = (const float*)d_in[4];   // (3H,)
  const float* br = (const float*)d_in[5];   // (3H,)
  float* out = (float*)d_out;                // (T,B,H)

  // workspace layout
  const size_t NW = (size_t)IDIM * N3H;          // 196608
  int8_t* Wq  = (int8_t*)d_ws;                   // 196608
  int8_t* Rq  = Wq + NW;                         // 196608
  int8_t* bx8 = Rq + NW;                         // 768
  int8_t* br8 = bx8 + N3H;                       // 768
  int8_t* WxQ8 = br8 + N3H;                      // 64*512*768 = 25165824

  {
    int total = (int)(2 * NW + 2 * N3H);
    int blocks = (total + 255) / 256;
    prep_kernel<<<blocks, 256, 0, stream>>>(W, R, bx, br, Wq, Rq, bx8, br8);
  }
  gemm_wx_kernel<<<T_STEPS, 768, 0, stream>>>(x, Wq, WxQ8);
  gru_rec4_kernel<<<BATCH, 256, 0, stream>>>(h0, Rq, bx8, br8, WxQ8, out);
}

// Round 6
// 473.923 us; speedup vs baseline: 1.1710x; 1.0707x over previous
//
#include <hip/hip_runtime.h>
#include <hip/hip_bf16.h>
#include <stdint.h>

// ---------------------------------------------------------------------------
// QuantGRU: T=512, B=64, I=256, H=256. ACT scale 2^-7, W scale 2^-8.
// Fully exact integer arithmetic; sigmoid/tanh via 256-entry f64-built LUTs.
// Recurrence: 256 thr/block (4 waves); h broadcast via readlane->SGPR->dot4;
// ALL-INTEGER gate math (no float temps) to keep the loop live-set < 256
// VGPRs so the 192 weight dwords stay register-resident (R5 showed
// VGPR_Count=112 => compiler shuttled weights through AGPRs every step).
// ---------------------------------------------------------------------------

#define T_STEPS 512
#define BATCH   64
#define IDIM    256
#define HDIM    256
#define N3H     768   // 3*H

#if defined(__has_builtin)
#if __has_builtin(__builtin_amdgcn_sdot4)
#define DOT4(a,b,c) __builtin_amdgcn_sdot4((int)(a),(int)(b),(int)(c),false)
#endif
#endif
#ifndef DOT4
__device__ __forceinline__ int dot4_sw(uint32_t a, uint32_t b, int c){
  c += (int)(int8_t)(a)      * (int)(int8_t)(b);
  c += (int)(int8_t)(a>>8)   * (int)(int8_t)(b>>8);
  c += (int)(int8_t)(a>>16)  * (int)(int8_t)(b>>16);
  c += (int)(int8_t)(a>>24)  * (int)(int8_t)(b>>24);
  return c;
}
#define DOT4(a,b,c) dot4_sw((uint32_t)(a),(uint32_t)(b),(int)(c))
#endif

// select dword component of a uint4 by compile-time constant (stays in VGPRs)
#define CHUNK(W,c) (((c)&3)==0 ? W[(c)>>2].x : ((c)&3)==1 ? W[(c)>>2].y : \
                    ((c)&3)==2 ? W[(c)>>2].z : W[(c)>>2].w)

// LDS-only workgroup barrier (no vmcnt drain; loads/stores stay in flight)
__device__ __forceinline__ void barrier_lds() {
  asm volatile("s_waitcnt lgkmcnt(0)\n\ts_barrier" ::: "memory");
}

// ---- exact integer round-to-nearest-even helpers (verified vs jnp.round) ---
__device__ __forceinline__ int clamp8(int x)   { return min(127, max(-128, x)); }
// rne(y/2):    y integer
__device__ __forceinline__ int rne_half(int y) { int t = y >> 1; return t + (t & y & 1); }
// rne(s/256):  s integer (arith shift = floor; tie -> even)
__device__ __forceinline__ int rne_s8(int s)   { return (s + 127 + ((s >> 8) & 1)) >> 8; }
// rne(p/128)
__device__ __forceinline__ int rne_s7(int p)   { return (p + 63 + ((p >> 7) & 1)) >> 7; }

// float RNE+clamp (host-side-equivalent quantize; used in prep/gemm only)
__device__ __forceinline__ int rneclamp(float v) {
  int q = (int)rintf(v);
  return min(127, max(-128, q));
}

__device__ __forceinline__ uint32_t packq4(float4 f, float sc) {
  uint32_t b0 = (uint32_t)(uint8_t)(int8_t)rneclamp(f.x * sc);
  uint32_t b1 = (uint32_t)(uint8_t)(int8_t)rneclamp(f.y * sc);
  uint32_t b2 = (uint32_t)(uint8_t)(int8_t)rneclamp(f.z * sc);
  uint32_t b3 = (uint32_t)(uint8_t)(int8_t)rneclamp(f.w * sc);
  return b0 | (b1 << 8) | (b2 << 16) | (b3 << 24);
}

// ---------------------------------------------------------------------------
// prep: W -> k-chunk-transposed int8 (for gemm_wx coalesced column loads),
// R -> plain column-major int8, biases -> int8.
// ---------------------------------------------------------------------------
__global__ void prep_kernel(const float* __restrict__ W, const float* __restrict__ R,
                            const float* __restrict__ bx, const float* __restrict__ br,
                            int8_t* __restrict__ Wq, int8_t* __restrict__ Rq,
                            int8_t* __restrict__ bx8, int8_t* __restrict__ br8) {
  const int NW = IDIM * N3H; // 196608
  int idx = blockIdx.x * 256 + threadIdx.x;
  if (idx < NW) {
    int k = idx / N3H, j = idx % N3H;
    Wq[((size_t)(k >> 4) * N3H + j) * 16 + (k & 15)] = (int8_t)rneclamp(W[idx] * 256.0f);
  } else if (idx < 2 * NW) {
    int i2 = idx - NW;
    int k = i2 / N3H, j = i2 % N3H;
    Rq[(size_t)j * HDIM + k] = (int8_t)rneclamp(R[i2] * 256.0f);   // col-major
  } else if (idx < 2 * NW + N3H) {
    int i2 = idx - 2 * NW;
    bx8[i2] = (int8_t)rneclamp(bx[i2] * 256.0f);
  } else if (idx < 2 * NW + 2 * N3H) {
    int i2 = idx - 2 * NW - N3H;
    br8[i2] = (int8_t)rneclamp(br[i2] * 256.0f);
  }
}

// ---------------------------------------------------------------------------
// gemm_wx: Wx_q[b][t][j] = clamp(rne( (fq(x) . Wq col j) / 256 ))  (int8)
// one block per t (64 rows), 768 threads = one per output column.
// ---------------------------------------------------------------------------
__global__ __launch_bounds__(768, 1) void gemm_wx_kernel(
    const float* __restrict__ x, const int8_t* __restrict__ Wq,
    int8_t* __restrict__ WxQ8) {
  const int t = blockIdx.x;   // 0..511
  const int j = threadIdx.x;  // 0..767

  __shared__ uint4 xq4[64 * 16];   // 64 rows x 256 int8 = 16KB
  uint32_t* xq = (uint32_t*)xq4;

  uint4 w[16];
  const uint4* wp = (const uint4*)Wq;
  #pragma unroll
  for (int kk = 0; kk < 16; ++kk) w[kk] = wp[kk * N3H + j];

  const float4* xg = (const float4*)(x) + (size_t)t * 4096;
  for (int i = j; i < 4096; i += 768) {
    float4 f = xg[i];
    xq[i] = packq4(f, 128.0f);
  }
  __syncthreads();

  for (int r = 0; r < 64; ++r) {
    int s = 0;
    #pragma unroll
    for (int kk = 0; kk < 16; ++kk) {
      uint4 hv = xq4[r * 16 + kk];
      s = DOT4(hv.x, w[kk].x, s);
      s = DOT4(hv.y, w[kk].y, s);
      s = DOT4(hv.z, w[kk].z, s);
      s = DOT4(hv.w, w[kk].w, s);
    }
    int q = clamp8(rne_s8(s));
    WxQ8[((size_t)r * T_STEPS + t) * N3H + j] = (int8_t)q;
  }
}

// ---------------------------------------------------------------------------
// gru_rec6: one block per batch element; 256 threads (4 waves), thread j owns
// h[j] and its gate triple (columns j, j+256, j+512 of R). All-integer step.
// ---------------------------------------------------------------------------
__global__ __launch_bounds__(256, 1) __attribute__((amdgpu_waves_per_eu(1, 1)))
void gru_rec6_kernel(
    const float* __restrict__ h0, const int8_t* __restrict__ Rq,
    const int8_t* __restrict__ bx8, const int8_t* __restrict__ br8,
    const int8_t* __restrict__ WxQ8, float* __restrict__ out) {
  const int b = blockIdx.x;     // batch element
  const int j = threadIdx.x;    // 0..255
  const int lane = j & 63;

  __shared__ uint32_t hq[2][64];    // double-buffered int8 h (256 B each)
  __shared__ int8_t lutS[256];
  __shared__ int8_t lutT[256];

  // R columns j, j+256, j+512 in registers: 3 x 16 uint4 = 192 VGPRs
  uint4 wz[16], wr[16], wg[16];
  {
    const uint4* pz = (const uint4*)(Rq + (size_t)j * HDIM);
    const uint4* pr = (const uint4*)(Rq + (size_t)(j + 256) * HDIM);
    const uint4* pg = (const uint4*)(Rq + (size_t)(j + 512) * HDIM);
    #pragma unroll
    for (int kk = 0; kk < 16; ++kk) { wz[kk] = pz[kk]; wr[kk] = pr[kk]; wg[kk] = pg[kk]; }
  }
  const int bz  = (int)bx8[j];
  const int brg = (int)bx8[j + 256];
  const int bg  = (int)bx8[j + 512];
  const int vbz = (int)br8[j];
  const int vbr = (int)br8[j + 256];
  const int vbg = (int)br8[j + 512];

  // LUTs in f64 (inputs are fq-clamped to k/128, k in [-128,127])
  {
    double a = ((double)j - 128.0) / 128.0;
    lutS[j] = (int8_t)min(127, max(-128, (int)rint(128.0 / (1.0 + exp(-a)))));
    lutT[j] = (int8_t)min(127, max(-128, (int)rint(128.0 * tanh(a))));
  }
  // h carried as exact integer hi (units 1/128); h0 is zeros in this problem.
  int hi = (int)rintf(h0[b * HDIM + j] * 128.0f);
  ((int8_t*)&hq[0][0])[j] = (int8_t)clamp8(hi);
  __syncthreads();

  const int8_t* wxp = WxQ8 + (size_t)b * T_STEPS * N3H + j;
  float* outp = out + (size_t)b * HDIM + j;

  // Wx 2-deep prefetch pipeline: A = step t, B = step t+1
  int wxA0 = (int)wxp[0],   wxA1 = (int)wxp[256],       wxA2 = (int)wxp[512];
  int wxB0 = (int)wxp[N3H], wxB1 = (int)wxp[N3H + 256], wxB2 = (int)wxp[N3H + 512];

  for (int t = 0; t < T_STEPS; ++t) {
    const int cur = t & 1, nxt = cur ^ 1;

    // issue Wx loads for t+2 first (~2 steps of latency hiding)
    const int8_t* p = wxp + (size_t)min(t + 2, T_STEPS - 1) * N3H;
    int nz = (int)p[0], nr = (int)p[256], ng = (int)p[512];

    // ---- GEMV: h broadcast via readlane -> SGPR, dot4 against reg weights
    uint32_t hw = hq[cur][lane];      // one ds_read_b32 per wave
    int sz = 0, sr = 0, sg = 0;
    #pragma unroll
    for (int c = 0; c < 64; ++c) {
      int hc = __builtin_amdgcn_readlane((int)hw, c);
      sz = DOT4(hc, CHUNK(wz, c), sz);
      sr = DOT4(hc, CHUNK(wr, c), sr);
      sg = DOT4(hc, CHUNK(wg, c), sg);
    }
    // v = fq(fq(s/2^15,7)+br,7)  -- all integer, exact
    int vz = clamp8(rne_half(2 * clamp8(rne_s8(sz)) + vbz));
    int vr = clamp8(rne_half(2 * clamp8(rne_s8(sr)) + vbr));
    int vg = clamp8(rne_half(2 * clamp8(rne_s8(sg)) + vbg));

    // gates (integer, exact)
    int az = clamp8(rne_half(2 * (wxA0 + vz) + bz));
    int zi = (int)lutS[az + 128];
    int ar = clamp8(rne_half(2 * (wxA1 + vr) + brg));
    int ri = (int)lutS[ar + 128];
    int rrh = clamp8(rne_s7(ri * vg));
    int ag = clamp8(rne_half(2 * (wxA2 + rrh) + bg));
    int gi = (int)lutT[ag + 128];
    int oldi = clamp8(rne_s7(zi * hi));
    int newi = clamp8(rne_s7((128 - zi) * gi));
    hi = oldi + newi;                       // integer, units 1/128
    outp[(size_t)t * BATCH * HDIM] = (float)hi * (1.0f / 128.0f);
    ((int8_t*)&hq[nxt][0])[j] = (int8_t)clamp8(hi);

    // advance Wx pipeline
    wxA0 = wxB0; wxA1 = wxB1; wxA2 = wxB2;
    wxB0 = nz;   wxB1 = nr;   wxB2 = ng;

    barrier_lds();   // LDS-only: hq[nxt] visible; vmcnt stays in flight
  }
}

// ---------------------------------------------------------------------------
extern "C" void kernel_launch(void* const* d_in, const int* in_sizes, int n_in,
                              void* d_out, int out_size, void* d_ws, size_t ws_size,
                              hipStream_t stream) {
  const float* x  = (const float*)d_in[0];   // (T,B,I)
  const float* h0 = (const float*)d_in[1];   // (B,H)
  const float* W  = (const float*)d_in[2];   // (I,3H)
  const float* R  = (const float*)d_in[3];   // (H,3H)
  const float* bx = (const float*)d_in[4];   // (3H,)
  const float* br = (const float*)d_in[5];   // (3H,)
  float* out = (float*)d_out;                // (T,B,H)

  // workspace layout
  const size_t NW = (size_t)IDIM * N3H;          // 196608
  int8_t* Wq  = (int8_t*)d_ws;                   // 196608
  int8_t* Rq  = Wq + NW;                         // 196608
  int8_t* bx8 = Rq + NW;                         // 768
  int8_t* br8 = bx8 + N3H;                       // 768
  int8_t* WxQ8 = br8 + N3H;                      // 64*512*768 = 25165824

  {
    int total = (int)(2 * NW + 2 * N3H);
    int blocks = (total + 255) / 256;
    prep_kernel<<<blocks, 256, 0, stream>>>(W, R, bx, br, Wq, Rq, bx8, br8);
  }
  gemm_wx_kernel<<<T_STEPS, 768, 0, stream>>>(x, Wq, WxQ8);
  gru_rec6_kernel<<<BATCH, 256, 0, stream>>>(h0, Rq, bx8, br8, WxQ8, out);
}